// Round 16
// baseline (374.672 us; speedup 1.0000x reference)
//
#include <hip/hip_runtime.h>

#define K_DIM 128

typedef __attribute__((ext_vector_type(8))) short short8;
typedef __attribute__((ext_vector_type(4))) float f32x4;

// ---- compile-time path tables: PATHS order = l1-major, l2, l3 ascending ----
constexpr int C_L1[34] = {0,0,0,0, 1,1,1,1,1,1,1,1,1, 2,2,2,2,2,2,2,2,2,2,2, 3,3,3,3,3,3,3,3,3,3};
constexpr int C_L2[34] = {0,1,2,3, 0,1,1,1,2,2,2,3,3, 0,1,1,1,2,2,2,2,3,3,3, 0,1,1,2,2,2,3,3,3,3};
constexpr int C_L3[34] = {0,1,2,3, 1,0,1,2,1,2,3,2,3, 2,1,2,3,0,1,2,3,1,2,3, 3,2,3,1,2,3,0,1,2,3};
constexpr int C_NP[4]  = {4,9,11,10};
constexpr int C_PL[4][11] = {
  {0,5,17,30, 0,0,0,0,0,0,0},
  {1,4,6,8,14,18,21,27,31, 0,0},
  {2,7,9,11,13,15,19,22,25,28,32},
  {3,10,12,16,20,23,24,26,29,33, 0}
};
constexpr int C_CSUM[4] = {0,8,26,48};      // 64-ch chunk base per l3
constexpr size_t FOFF[4] = {0, 1048576, 4194304, 9437184};  // per-l elem offsets
constexpr int FSZ[4] = {1048576, 3145728, 5242880, 7340032};
constexpr size_t FTOT = 16777216;           // elems per f-set

__device__ double dfactd(int n){ double r=1.0; for(int i=2;i<=n;++i) r*=(double)i; return r; }

__device__ __forceinline__ unsigned short f2bf(float x) {
    unsigned int b = __float_as_uint(x);
    return (unsigned short)((b + 0x7FFFu + ((b >> 16) & 1u)) >> 16);
}
__device__ __forceinline__ float bflo(unsigned int u){ return __uint_as_float(u << 16); }
__device__ __forceinline__ float bfhi(unsigned int u){ return __uint_as_float(u & 0xFFFF0000u); }

__device__ __forceinline__ unsigned int cvtpk(float lo, float hi) {
    unsigned int r;
    asm("v_cvt_pk_bf16_f32 %0, %1, %2" : "=v"(r) : "v"(lo), "v"(hi));
    return r;
}

// C2[p][m1i][m2i], 34*49 floats at d_ws+0
__global__ void cg_init(float* __restrict__ C2) {
    int e = blockIdx.x*blockDim.x + threadIdx.x;
    if (e >= 34*49) return;
    int p = e/49, r = e%49, m1i = r/7, m2i = r%7;
    int l1 = C_L1[p], l2 = C_L2[p], l3 = C_L3[p];
    float val = 0.f;
    if (m1i < 2*l1+1 && m2i < 2*l2+1) {
        int m1 = m1i-l1, m2 = m2i-l2, m3 = m1+m2;
        if (m3 >= -l3 && m3 <= l3) {
            double pref = sqrt((double)(2*l3+1) * dfactd(l3+l1-l2)*dfactd(l3-l1+l2)
                               * dfactd(l1+l2-l3) / dfactd(l1+l2+l3+1));
            pref *= sqrt(dfactd(l3+m3)*dfactd(l3-m3)*dfactd(l1-m1)*dfactd(l1+m1)
                         *dfactd(l2-m2)*dfactd(l2+m2));
            int kmin = max(0, max(l2-l3-m1, l1-l3+m2));
            int kmax = min(l1+l2-l3, min(l1-m1, l2+m2));
            double s = 0.0;
            for (int k=kmin;k<=kmax;++k) {
                double t = dfactd(k)*dfactd(l1+l2-l3-k)*dfactd(l1-m1-k)
                         * dfactd(l2+m2-k)*dfactd(l3-l2+m1+k)*dfactd(l3-l1-m2+k);
                s += ((k&1)? -1.0:1.0)/t;
            }
            val = (float)(pref*s);
        }
    }
    C2[e] = val;
}

// W -> bf16 transposed+swizzled tiles: chunk c elem col*64 + (kk ^ ((col&7)<<3))
__global__ void wt_prep(const float* __restrict__ W0, const float* __restrict__ W1,
                        const float* __restrict__ W2, const float* __restrict__ W3,
                        unsigned short* __restrict__ wt) {
    int b = blockIdx.x;
    int chunk = b >> 5;
    int e = ((b & 31) << 8) + threadIdx.x;
    int kk = e & 63, col = e >> 6;
    int l3 = (chunk < 8) ? 0 : (chunk < 26) ? 1 : (chunk < 48) ? 2 : 3;
    int local = chunk - C_CSUM[l3];
    int kin = local*64 + kk;
    const float* W = (l3==0)?W0:(l3==1)?W1:(l3==2)?W2:W3;
    float v = W[(size_t)kin*K_DIM + col];
    wt[(size_t)chunk*8192 + col*64 + (kk ^ ((col&7)<<3))] = f2bf(v);
}

// f1/f2 -> bf16 packed copies in ws
__global__ void fpack(const float* __restrict__ s0, const float* __restrict__ s1,
                      const float* __restrict__ s2, const float* __restrict__ s3,
                      const float* __restrict__ s4, const float* __restrict__ s5,
                      const float* __restrict__ s6, const float* __restrict__ s7,
                      unsigned short* __restrict__ dst) {
    int y = blockIdx.y;
    int l = y & 3, fi = y >> 2;
    const float* srcs[8] = {s0,s1,s2,s3,s4,s5,s6,s7};
    const float* src = srcs[y];
    int i4 = blockIdx.x*256 + threadIdx.x;
    if (i4*4 >= FSZ[l]) return;
    float4 v = reinterpret_cast<const float4*>(src)[i4];
    unsigned int u0 = (unsigned int)f2bf(v.x) | ((unsigned int)f2bf(v.y) << 16);
    unsigned int u1 = (unsigned int)f2bf(v.z) | ((unsigned int)f2bf(v.w) << 16);
    unsigned short* d = dst + fi*FTOT + FOFF[l] + (size_t)i4*4;
    *reinterpret_cast<uint2*>(d) = make_uint2(u0, u1);
}

// TP for one path (both halves): q1 resident, q2 streamed; swizzled A write
// with one zero pad-row per node (row stride TL3+1).
template<int L3, int PI>
__device__ __forceinline__ void tp_into(
    const unsigned int (&q1)[16][2], const unsigned int (&q2s)[7][2],
    const float* __restrict__ C2slot, unsigned char* __restrict__ Ab,
    int nodel, int chq)
{
    constexpr int P  = C_PL[L3][PI];
    constexpr int l1 = C_L1[P], l2 = C_L2[P];
    constexpr int d1 = 2*l1+1, d2 = 2*l2+1;
    constexpr int TL3 = 2*L3+1;
    constexpr int STR = TL3+1;
    #pragma unroll
    for (int h=0; h<2; ++h) {
        float a[TL3][2];
        #pragma unroll
        for (int mt=0;mt<TL3;++mt){ a[mt][0]=0.f; a[mt][1]=0.f; }
        #pragma unroll
        for (int m2i=0; m2i<d2; ++m2i) {
            float y0 = bflo(q2s[m2i][h]);
            float y1 = bfhi(q2s[m2i][h]);
            #pragma unroll
            for (int m1i=0; m1i<d1; ++m1i) {
                int mt = (m1i-l1) + (m2i-l2) + L3;
                if (mt >= 0 && mt < TL3) {         // folds at compile time
                    float c = C2slot[m1i*7 + m2i];
                    a[mt][0] = fmaf(c*bflo(q1[l1*l1+m1i][h]), y0, a[mt][0]);
                    a[mt][1] = fmaf(c*bfhi(q1[l1*l1+m1i][h]), y1, a[mt][1]);
                }
            }
        }
        #pragma unroll
        for (int mt=0; mt<TL3; ++mt) {
            int row = nodel*STR + mt;
            *reinterpret_cast<unsigned int*>(
                Ab + row*256 + ((h*128 + chq*4) ^ ((row&7)<<4))) = cvtpk(a[mt][0], a[mt][1]);
        }
        {   // zero pad row
            int row = nodel*STR + TL3;
            *reinterpret_cast<unsigned int*>(
                Ab + row*256 + ((h*128 + chq*4) ^ ((row&7)<<4))) = 0u;
        }
    }
}

// W fragments for this wave's 2 columns, 4 K-steps each
template<int L3, int PI>
__device__ __forceinline__ void load_wf(const unsigned short* __restrict__ wt,
                                        int wid, int lr, int lg, short8 (&wf)[2][4]) {
    const unsigned char* wb0 = (const unsigned char*)(wt + (size_t)(C_CSUM[L3] + PI*2    )*8192);
    const unsigned char* wb1 = (const unsigned char*)(wt + (size_t)(C_CSUM[L3] + PI*2 + 1)*8192);
    #pragma unroll
    for (int j=0;j<2;++j) {
        int col = 16*(2*wid+j) + lr;
        int wkey = (col&7)<<4;
        wf[j][0] = *reinterpret_cast<const short8*>(wb0 + col*128 + ((16*lg     ) ^ wkey));
        wf[j][1] = *reinterpret_cast<const short8*>(wb0 + col*128 + ((16*lg + 64) ^ wkey));
        wf[j][2] = *reinterpret_cast<const short8*>(wb1 + col*128 + ((16*lg     ) ^ wkey));
        wf[j][3] = *reinterpret_cast<const short8*>(wb1 + col*128 + ((16*lg + 64) ^ wkey));
    }
}

// MFMA: wave covers 2 col-tiles x RT row-tiles x 4 ksteps; A-read reused for 2 cols
template<int L3>
__device__ __forceinline__ void mfma_from(
    const unsigned char* __restrict__ Ab, const short8 (&wf)[2][4],
    int lr, int lg, f32x4 (&acc)[2][L3+1])
{
    constexpr int RT = L3+1;
    #pragma unroll
    for (int kst=0; kst<4; ++kst) {
        #pragma unroll
        for (int rt=0; rt<RT; ++rt) {
            int arow = 16*rt + lr;
            short8 af = *reinterpret_cast<const short8*>(
                Ab + arow*256 + ((16*lg + 64*kst) ^ ((arow&7)<<4)));
            acc[0][rt] = __builtin_amdgcn_mfma_f32_16x16x32_bf16(af, wf[0][kst], acc[0][rt], 0, 0, 0);
            acc[1][rt] = __builtin_amdgcn_mfma_f32_16x16x32_bf16(af, wf[1][kst], acc[1][rt], 0, 0, 0);
        }
    }
}

template<int L3, int PI>
__device__ __forceinline__ void stream_f2(
    const unsigned short* __restrict__ f2b, int n0, int nodel, int chq,
    unsigned int (&q2s)[7][2])
{
    constexpr int P  = C_PL[L3][PI];
    constexpr int l2 = C_L2[P];
    constexpr int d2 = 2*l2+1;
    const unsigned short* g2 = f2b + FOFF[l2] + (size_t)(n0+nodel)*(d2*128) + chq*2;
    #pragma unroll
    for (int m=0;m<d2;++m) {
        q2s[m][0] = *reinterpret_cast<const unsigned int*>(g2 + m*128);
        q2s[m][1] = *reinterpret_cast<const unsigned int*>(g2 + m*128 + 64);
    }
}

// Pipelined path chain: {wf(PI); C2s(PI+2) preload; f2(PI+1) stream;
// TP(PI+1)->buf[(PI+1)&1]; MFMA(PI)<-buf[PI&1]; barrier}
template<int L3, int PI>
__device__ __forceinline__ void pipe(
    const unsigned int (&q1)[16][2], unsigned int (&q2s)[7][2],
    const unsigned short* __restrict__ f2b,
    const unsigned short* __restrict__ wt, const float* __restrict__ C2,
    float (&C2s)[2][49], unsigned char* A0, unsigned char* A1,
    int tid, int n0, int nodel, int chq, int wid, int lr, int lg,
    f32x4 (&acc)[2][L3+1])
{
    constexpr int NP = C_NP[L3];
    short8 wf[2][4];
    load_wf<L3, PI>(wt, wid, lr, lg, wf);
    if constexpr (PI+2 < NP) {
        if (tid < 49) C2s[PI&1][tid] = C2[C_PL[L3][PI+2]*49 + tid];
    }
    if constexpr (PI+1 < NP) {
        stream_f2<L3, PI+1>(f2b, n0, nodel, chq, q2s);
        tp_into<L3, PI+1>(q1, q2s, C2s[(PI+1)&1], ((PI+1)&1) ? A1 : A0, nodel, chq);
    }
    mfma_from<L3>((PI&1) ? A1 : A0, wf, lr, lg, acc);
    __syncthreads();
    if constexpr (PI+1 < NP)
        pipe<L3, PI+1>(q1, q2s, f2b, wt, C2, C2s, A0, A1,
                       tid, n0, nodel, chq, wid, lr, lg, acc);
}

template<int L3>
__device__ __forceinline__ void run8(
    int n0,
    const unsigned short* __restrict__ f1b, const unsigned short* __restrict__ f2b,
    const unsigned short* __restrict__ wt, const float* __restrict__ C2,
    float* __restrict__ out, float (&C2s)[2][49], unsigned char* Asb)
{
    constexpr int TL3 = 2*L3+1;
    constexpr int STR = TL3+1;
    constexpr int RT  = L3+1;
    constexpr int NP  = C_NP[L3];
    const int tid   = threadIdx.x;
    const int nodel = tid >> 5;       // 0..7
    const int chq   = tid & 31;       // 2-ch chunk
    const int lane  = tid & 63, wid = tid >> 6;   // 4 waves
    const int lr    = lane & 15, lg = lane >> 4;
    constexpr size_t OB = FOFF[L3];
    unsigned char* A0 = Asb;
    unsigned char* A1 = Asb + 16384;

    // prologue: resident f1 loads (all rows, once)
    unsigned int q1[16][2];
    #pragma unroll
    for (int l=0; l<4; ++l) {
        const unsigned short* g1 = f1b + FOFF[l] + (size_t)(n0+nodel)*((2*l+1)*128) + chq*2;
        #pragma unroll
        for (int m=0; m<2*l+1; ++m) {
            q1[l*l+m][0] = *reinterpret_cast<const unsigned int*>(g1 + m*128);
            q1[l*l+m][1] = *reinterpret_cast<const unsigned int*>(g1 + m*128 + 64);
        }
    }
    unsigned int q2s[7][2];

    f32x4 acc[2][RT];
    #pragma unroll
    for (int j=0;j<2;++j)
        #pragma unroll
        for (int rt=0; rt<RT; ++rt) acc[j][rt] = (f32x4){0.f,0.f,0.f,0.f};

    if (tid < 49) {
        C2s[0][tid] = C2[C_PL[L3][0]*49 + tid];
        if constexpr (NP > 1) C2s[1][tid] = C2[C_PL[L3][1]*49 + tid];
    }
    __syncthreads();
    stream_f2<L3, 0>(f2b, n0, nodel, chq, q2s);
    tp_into<L3, 0>(q1, q2s, C2s[0], A0, nodel, chq);
    __syncthreads();
    pipe<L3, 0>(q1, q2s, f2b, wt, C2, C2s, A0, A1,
                tid, n0, nodel, chq, wid, lr, lg, acc);

    // epilogue: padded restage (stride 132) -> coalesced store of REAL rows
    float* S = reinterpret_cast<float*>(Asb);
    const unsigned short* __restrict__ fr = f1b + OB;
    #pragma unroll
    for (int j=0;j<2;++j) {
        int col = 16*(2*wid+j) + lr;
        #pragma unroll
        for (int rt=0; rt<RT; ++rt)
            #pragma unroll
            for (int i=0;i<4;++i)
                S[(16*rt + 4*lg + i)*132 + col] = acc[j][rt][i];
    }
    __syncthreads();
    constexpr int RR = 8*TL3;            // real rows
    #pragma unroll
    for (int it=0; it*256 < RR*32; ++it) {
        int s = tid + it*256;
        if (s < RR*32) {
            int rr = s >> 5, cq = (s & 31) * 4;
            int nd = rr / TL3;           // constexpr divisor -> magic mul
            int mt = rr - nd*TL3;
            int prow = nd*STR + mt;
            size_t ro = (size_t)((n0+nd)*TL3 + mt) * K_DIM;
            float4 v = *reinterpret_cast<const float4*>(&S[prow*132 + cq]);
            uint2 rb = *reinterpret_cast<const uint2*>(fr + ro + cq);
            v.x += bflo(rb.x); v.y += bfhi(rb.x);
            v.z += bflo(rb.y); v.w += bfhi(rb.y);
            *reinterpret_cast<float4*>(&out[OB + ro + cq]) = v;
        }
    }
}

__global__ __launch_bounds__(256, 4) void cg_main(
    const unsigned short* __restrict__ f1b, const unsigned short* __restrict__ f2b,
    const unsigned short* __restrict__ wt,
    const float* __restrict__ C2, float* __restrict__ out)
{
    __shared__ __align__(16) unsigned char Asb[34304]; // dbuf 2x16KB / epi 33.8KB
    __shared__ float C2s[2][49];

    // Schedule: x = XCD (bid&7); per XCD 512 blocks = 64 rounds x 8 blocks
    // (2 per l3, 8 nodes each); a round covers one 16-node slice for all l3.
    int bid = blockIdx.x;
    int x = bid & 7, j = bid >> 3;
    int rnd = j >> 3, k = j & 7;
    int l3 = k >> 1, q = k & 1;
    int n0 = x*1024 + rnd*16 + q*8;
    if (l3 == 0)      run8<0>(n0, f1b, f2b, wt, C2, out, C2s, Asb);
    else if (l3 == 1) run8<1>(n0, f1b, f2b, wt, C2, out, C2s, Asb);
    else if (l3 == 2) run8<2>(n0, f1b, f2b, wt, C2, out, C2s, Asb);
    else              run8<3>(n0, f1b, f2b, wt, C2, out, C2s, Asb);
}

extern "C" void kernel_launch(void* const* d_in, const int* in_sizes, int n_in,
                              void* d_out, int out_size, void* d_ws, size_t ws_size,
                              hipStream_t stream) {
    const float* f10 = (const float*)d_in[0];
    const float* f20 = (const float*)d_in[1];
    const float* W0  = (const float*)d_in[2];
    const float* f11 = (const float*)d_in[3];
    const float* f21 = (const float*)d_in[4];
    const float* W1  = (const float*)d_in[5];
    const float* f12 = (const float*)d_in[6];
    const float* f22 = (const float*)d_in[7];
    const float* W2  = (const float*)d_in[8];
    const float* f13 = (const float*)d_in[9];
    const float* f23 = (const float*)d_in[10];
    const float* W3  = (const float*)d_in[11];

    float* C2 = (float*)d_ws;                                       // 6664 B
    unsigned short* wtw = (unsigned short*)((char*)d_ws + 8192);    // 1.09 MB
    unsigned short* f1b = (unsigned short*)((char*)d_ws + 1122304); // 32 MB
    unsigned short* f2b = f1b + FTOT;                               // 32 MB
    float* out = (float*)d_out;

    hipLaunchKernelGGL(cg_init, dim3(7), dim3(256), 0, stream, C2);
    hipLaunchKernelGGL(wt_prep, dim3(68*32), dim3(256), 0, stream, W0, W1, W2, W3, wtw);
    hipLaunchKernelGGL(fpack, dim3(7168, 8), dim3(256), 0, stream,
        f10, f11, f12, f13, f20, f21, f22, f23, f1b);
    hipLaunchKernelGGL(cg_main, dim3(4096), dim3(256), 0, stream,
        f1b, f2b, wtw, C2, out);
}

// Round 17
// 246.695 us; speedup vs baseline: 1.5188x; 1.5188x over previous
//
#include <hip/hip_runtime.h>

#define K_DIM 128

typedef __attribute__((ext_vector_type(8))) short short8;
typedef __attribute__((ext_vector_type(4))) float f32x4;

// ---- compile-time path tables: PATHS order = l1-major, l2, l3 ascending ----
constexpr int C_L1[34] = {0,0,0,0, 1,1,1,1,1,1,1,1,1, 2,2,2,2,2,2,2,2,2,2,2, 3,3,3,3,3,3,3,3,3,3};
constexpr int C_L2[34] = {0,1,2,3, 0,1,1,1,2,2,2,3,3, 0,1,1,1,2,2,2,2,3,3,3, 0,1,1,2,2,2,3,3,3,3};
constexpr int C_L3[34] = {0,1,2,3, 1,0,1,2,1,2,3,2,3, 2,1,2,3,0,1,2,3,1,2,3, 3,2,3,1,2,3,0,1,2,3};
constexpr int C_NP[4]  = {4,9,11,10};
constexpr int C_PL[4][11] = {
  {0,5,17,30, 0,0,0,0,0,0,0},
  {1,4,6,8,14,18,21,27,31, 0,0},
  {2,7,9,11,13,15,19,22,25,28,32},
  {3,10,12,16,20,23,24,26,29,33, 0}
};
constexpr int C_CSUM[4] = {0,8,26,48};      // 64-ch chunk base per l3
constexpr size_t FOFF[4] = {0, 1048576, 4194304, 9437184};  // per-l elem offsets
constexpr int FSZ[4] = {1048576, 3145728, 5242880, 7340032};
constexpr size_t FTOT = 16777216;           // elems per f-set

__device__ double dfactd(int n){ double r=1.0; for(int i=2;i<=n;++i) r*=(double)i; return r; }

__device__ __forceinline__ unsigned short f2bf(float x) {
    unsigned int b = __float_as_uint(x);
    return (unsigned short)((b + 0x7FFFu + ((b >> 16) & 1u)) >> 16);
}
__device__ __forceinline__ float bflo(unsigned int u){ return __uint_as_float(u << 16); }
__device__ __forceinline__ float bfhi(unsigned int u){ return __uint_as_float(u & 0xFFFF0000u); }

__device__ __forceinline__ unsigned int cvtpk(float lo, float hi) {
    unsigned int r;
    asm("v_cvt_pk_bf16_f32 %0, %1, %2" : "=v"(r) : "v"(lo), "v"(hi));
    return r;
}

// C2[p][m1i][m2i], 34*49 floats at d_ws+0
__global__ void cg_init(float* __restrict__ C2) {
    int e = blockIdx.x*blockDim.x + threadIdx.x;
    if (e >= 34*49) return;
    int p = e/49, r = e%49, m1i = r/7, m2i = r%7;
    int l1 = C_L1[p], l2 = C_L2[p], l3 = C_L3[p];
    float val = 0.f;
    if (m1i < 2*l1+1 && m2i < 2*l2+1) {
        int m1 = m1i-l1, m2 = m2i-l2, m3 = m1+m2;
        if (m3 >= -l3 && m3 <= l3) {
            double pref = sqrt((double)(2*l3+1) * dfactd(l3+l1-l2)*dfactd(l3-l1+l2)
                               * dfactd(l1+l2-l3) / dfactd(l1+l2+l3+1));
            pref *= sqrt(dfactd(l3+m3)*dfactd(l3-m3)*dfactd(l1-m1)*dfactd(l1+m1)
                         *dfactd(l2-m2)*dfactd(l2+m2));
            int kmin = max(0, max(l2-l3-m1, l1-l3+m2));
            int kmax = min(l1+l2-l3, min(l1-m1, l2+m2));
            double s = 0.0;
            for (int k=kmin;k<=kmax;++k) {
                double t = dfactd(k)*dfactd(l1+l2-l3-k)*dfactd(l1-m1-k)
                         * dfactd(l2+m2-k)*dfactd(l3-l2+m1+k)*dfactd(l3-l1-m2+k);
                s += ((k&1)? -1.0:1.0)/t;
            }
            val = (float)(pref*s);
        }
    }
    C2[e] = val;
}

// W -> bf16 transposed+swizzled tiles: chunk c elem col*64 + (kk ^ ((col&7)<<3))
__global__ void wt_prep(const float* __restrict__ W0, const float* __restrict__ W1,
                        const float* __restrict__ W2, const float* __restrict__ W3,
                        unsigned short* __restrict__ wt) {
    int b = blockIdx.x;
    int chunk = b >> 5;
    int e = ((b & 31) << 8) + threadIdx.x;
    int kk = e & 63, col = e >> 6;
    int l3 = (chunk < 8) ? 0 : (chunk < 26) ? 1 : (chunk < 48) ? 2 : 3;
    int local = chunk - C_CSUM[l3];
    int kin = local*64 + kk;
    const float* W = (l3==0)?W0:(l3==1)?W1:(l3==2)?W2:W3;
    float v = W[(size_t)kin*K_DIM + col];
    wt[(size_t)chunk*8192 + col*64 + (kk ^ ((col&7)<<3))] = f2bf(v);
}

// f1/f2 -> bf16 packed copies in ws
__global__ void fpack(const float* __restrict__ s0, const float* __restrict__ s1,
                      const float* __restrict__ s2, const float* __restrict__ s3,
                      const float* __restrict__ s4, const float* __restrict__ s5,
                      const float* __restrict__ s6, const float* __restrict__ s7,
                      unsigned short* __restrict__ dst) {
    int y = blockIdx.y;
    int l = y & 3, fi = y >> 2;
    const float* srcs[8] = {s0,s1,s2,s3,s4,s5,s6,s7};
    const float* src = srcs[y];
    int i4 = blockIdx.x*256 + threadIdx.x;
    if (i4*4 >= FSZ[l]) return;
    float4 v = reinterpret_cast<const float4*>(src)[i4];
    unsigned int u0 = (unsigned int)f2bf(v.x) | ((unsigned int)f2bf(v.y) << 16);
    unsigned int u1 = (unsigned int)f2bf(v.z) | ((unsigned int)f2bf(v.w) << 16);
    unsigned short* d = dst + fi*FTOT + FOFF[l] + (size_t)i4*4;
    *reinterpret_cast<uint2*>(d) = make_uint2(u0, u1);
}

// TP for one path (both halves): q1 resident, q2 streamed; swizzled A write
// with one zero pad-row per node (row stride TL3+1).
template<int L3, int PI>
__device__ __forceinline__ void tp_into(
    const unsigned int (&q1)[16][2], const unsigned int (&q2s)[7][2],
    const float* __restrict__ C2slot, unsigned char* __restrict__ Ab,
    int nodel, int chq)
{
    constexpr int P  = C_PL[L3][PI];
    constexpr int l1 = C_L1[P], l2 = C_L2[P];
    constexpr int d1 = 2*l1+1, d2 = 2*l2+1;
    constexpr int TL3 = 2*L3+1;
    constexpr int STR = TL3+1;
    #pragma unroll
    for (int h=0; h<2; ++h) {
        float a[TL3][2];
        #pragma unroll
        for (int mt=0;mt<TL3;++mt){ a[mt][0]=0.f; a[mt][1]=0.f; }
        #pragma unroll
        for (int m2i=0; m2i<d2; ++m2i) {
            float y0 = bflo(q2s[m2i][h]);
            float y1 = bfhi(q2s[m2i][h]);
            #pragma unroll
            for (int m1i=0; m1i<d1; ++m1i) {
                int mt = (m1i-l1) + (m2i-l2) + L3;
                if (mt >= 0 && mt < TL3) {         // folds at compile time
                    float c = C2slot[m1i*7 + m2i];
                    a[mt][0] = fmaf(c*bflo(q1[l1*l1+m1i][h]), y0, a[mt][0]);
                    a[mt][1] = fmaf(c*bfhi(q1[l1*l1+m1i][h]), y1, a[mt][1]);
                }
            }
        }
        #pragma unroll
        for (int mt=0; mt<TL3; ++mt) {
            int row = nodel*STR + mt;
            *reinterpret_cast<unsigned int*>(
                Ab + row*256 + ((h*128 + chq*4) ^ ((row&7)<<4))) = cvtpk(a[mt][0], a[mt][1]);
        }
        {   // zero pad row
            int row = nodel*STR + TL3;
            *reinterpret_cast<unsigned int*>(
                Ab + row*256 + ((h*128 + chq*4) ^ ((row&7)<<4))) = 0u;
        }
    }
}

// W fragments for this wave's 2 columns, 4 K-steps each
template<int L3, int PI>
__device__ __forceinline__ void load_wf(const unsigned short* __restrict__ wt,
                                        int wid, int lr, int lg, short8 (&wf)[2][4]) {
    const unsigned char* wb0 = (const unsigned char*)(wt + (size_t)(C_CSUM[L3] + PI*2    )*8192);
    const unsigned char* wb1 = (const unsigned char*)(wt + (size_t)(C_CSUM[L3] + PI*2 + 1)*8192);
    #pragma unroll
    for (int j=0;j<2;++j) {
        int col = 16*(2*wid+j) + lr;
        int wkey = (col&7)<<4;
        wf[j][0] = *reinterpret_cast<const short8*>(wb0 + col*128 + ((16*lg     ) ^ wkey));
        wf[j][1] = *reinterpret_cast<const short8*>(wb0 + col*128 + ((16*lg + 64) ^ wkey));
        wf[j][2] = *reinterpret_cast<const short8*>(wb1 + col*128 + ((16*lg     ) ^ wkey));
        wf[j][3] = *reinterpret_cast<const short8*>(wb1 + col*128 + ((16*lg + 64) ^ wkey));
    }
}

// MFMA: wave covers 2 col-tiles x RT row-tiles x 4 ksteps; A-read reused for 2 cols
template<int L3>
__device__ __forceinline__ void mfma_from(
    const unsigned char* __restrict__ Ab, const short8 (&wf)[2][4],
    int lr, int lg, f32x4 (&acc)[2][L3+1])
{
    constexpr int RT = L3+1;
    #pragma unroll
    for (int kst=0; kst<4; ++kst) {
        #pragma unroll
        for (int rt=0; rt<RT; ++rt) {
            int arow = 16*rt + lr;
            short8 af = *reinterpret_cast<const short8*>(
                Ab + arow*256 + ((16*lg + 64*kst) ^ ((arow&7)<<4)));
            acc[0][rt] = __builtin_amdgcn_mfma_f32_16x16x32_bf16(af, wf[0][kst], acc[0][rt], 0, 0, 0);
            acc[1][rt] = __builtin_amdgcn_mfma_f32_16x16x32_bf16(af, wf[1][kst], acc[1][rt], 0, 0, 0);
        }
    }
}

template<int L3, int PI>
__device__ __forceinline__ void stream_f2(
    const unsigned short* __restrict__ f2b, int n0, int nodel, int chq,
    unsigned int (&q2s)[7][2])
{
    constexpr int P  = C_PL[L3][PI];
    constexpr int l2 = C_L2[P];
    constexpr int d2 = 2*l2+1;
    const unsigned short* g2 = f2b + FOFF[l2] + (size_t)(n0+nodel)*(d2*128) + chq*2;
    #pragma unroll
    for (int m=0;m<d2;++m) {
        q2s[m][0] = *reinterpret_cast<const unsigned int*>(g2 + m*128);
        q2s[m][1] = *reinterpret_cast<const unsigned int*>(g2 + m*128 + 64);
    }
}

// Pipelined path chain: {wf(PI); C2s(PI+2) preload; f2(PI+1) stream;
// TP(PI+1)->buf[(PI+1)&1]; MFMA(PI)<-buf[PI&1]; barrier}
template<int L3, int PI>
__device__ __forceinline__ void pipe(
    const unsigned int (&q1)[16][2], unsigned int (&q2s)[7][2],
    const unsigned short* __restrict__ f2b,
    const unsigned short* __restrict__ wt, const float* __restrict__ C2,
    float (&C2s)[2][49], unsigned char* A0, unsigned char* A1,
    int tid, int n0, int nodel, int chq, int wid, int lr, int lg,
    f32x4 (&acc)[2][L3+1])
{
    constexpr int NP = C_NP[L3];
    short8 wf[2][4];
    load_wf<L3, PI>(wt, wid, lr, lg, wf);
    if constexpr (PI+2 < NP) {
        if (tid < 49) C2s[PI&1][tid] = C2[C_PL[L3][PI+2]*49 + tid];
    }
    if constexpr (PI+1 < NP) {
        stream_f2<L3, PI+1>(f2b, n0, nodel, chq, q2s);
        tp_into<L3, PI+1>(q1, q2s, C2s[(PI+1)&1], ((PI+1)&1) ? A1 : A0, nodel, chq);
    }
    mfma_from<L3>((PI&1) ? A1 : A0, wf, lr, lg, acc);
    __syncthreads();
    if constexpr (PI+1 < NP)
        pipe<L3, PI+1>(q1, q2s, f2b, wt, C2, C2s, A0, A1,
                       tid, n0, nodel, chq, wid, lr, lg, acc);
}

template<int L3>
__device__ __forceinline__ void run8(
    int n0,
    const unsigned short* __restrict__ f1b, const unsigned short* __restrict__ f2b,
    const unsigned short* __restrict__ wt, const float* __restrict__ C2,
    float* __restrict__ out, float (&C2s)[2][49], unsigned char* Asb)
{
    constexpr int TL3 = 2*L3+1;
    constexpr int STR = TL3+1;
    constexpr int RT  = L3+1;
    constexpr int NP  = C_NP[L3];
    const int tid   = threadIdx.x;
    const int nodel = tid >> 5;       // 0..7
    const int chq   = tid & 31;       // 2-ch chunk
    const int lane  = tid & 63, wid = tid >> 6;   // 4 waves
    const int lr    = lane & 15, lg = lane >> 4;
    constexpr size_t OB = FOFF[L3];
    unsigned char* A0 = Asb;
    unsigned char* A1 = Asb + 16384;

    // prologue: resident f1 loads (all rows, once)
    unsigned int q1[16][2];
    #pragma unroll
    for (int l=0; l<4; ++l) {
        const unsigned short* g1 = f1b + FOFF[l] + (size_t)(n0+nodel)*((2*l+1)*128) + chq*2;
        #pragma unroll
        for (int m=0; m<2*l+1; ++m) {
            q1[l*l+m][0] = *reinterpret_cast<const unsigned int*>(g1 + m*128);
            q1[l*l+m][1] = *reinterpret_cast<const unsigned int*>(g1 + m*128 + 64);
        }
    }
    unsigned int q2s[7][2];

    f32x4 acc[2][RT];
    #pragma unroll
    for (int j=0;j<2;++j)
        #pragma unroll
        for (int rt=0; rt<RT; ++rt) acc[j][rt] = (f32x4){0.f,0.f,0.f,0.f};

    if (tid < 49) {
        C2s[0][tid] = C2[C_PL[L3][0]*49 + tid];
        if constexpr (NP > 1) C2s[1][tid] = C2[C_PL[L3][1]*49 + tid];
    }
    __syncthreads();
    stream_f2<L3, 0>(f2b, n0, nodel, chq, q2s);
    tp_into<L3, 0>(q1, q2s, C2s[0], A0, nodel, chq);
    __syncthreads();
    pipe<L3, 0>(q1, q2s, f2b, wt, C2, C2s, A0, A1,
                tid, n0, nodel, chq, wid, lr, lg, acc);

    // epilogue: padded restage (stride 132) -> coalesced store of REAL rows
    float* S = reinterpret_cast<float*>(Asb);
    const unsigned short* __restrict__ fr = f1b + OB;
    #pragma unroll
    for (int j=0;j<2;++j) {
        int col = 16*(2*wid+j) + lr;
        #pragma unroll
        for (int rt=0; rt<RT; ++rt)
            #pragma unroll
            for (int i=0;i<4;++i)
                S[(16*rt + 4*lg + i)*132 + col] = acc[j][rt][i];
    }
    __syncthreads();
    constexpr int RR = 8*TL3;            // real rows
    #pragma unroll
    for (int it=0; it*256 < RR*32; ++it) {
        int s = tid + it*256;
        if (s < RR*32) {
            int rr = s >> 5, cq = (s & 31) * 4;
            int nd = rr / TL3;           // constexpr divisor -> magic mul
            int mt = rr - nd*TL3;
            int prow = nd*STR + mt;
            size_t ro = (size_t)((n0+nd)*TL3 + mt) * K_DIM;
            float4 v = *reinterpret_cast<const float4*>(&S[prow*132 + cq]);
            uint2 rb = *reinterpret_cast<const uint2*>(fr + ro + cq);
            v.x += bflo(rb.x); v.y += bfhi(rb.x);
            v.z += bflo(rb.y); v.w += bfhi(rb.y);
            *reinterpret_cast<float4*>(&out[OB + ro + cq]) = v;
        }
    }
}

__global__ __launch_bounds__(256) void cg_main(
    const unsigned short* __restrict__ f1b, const unsigned short* __restrict__ f2b,
    const unsigned short* __restrict__ wt,
    const float* __restrict__ C2, float* __restrict__ out)
{
    __shared__ __align__(16) unsigned char Asb[34304]; // dbuf 2x16KB / epi 33.8KB
    __shared__ float C2s[2][49];

    // Schedule: x = XCD (bid&7); per XCD 512 blocks = 64 rounds x 8 blocks
    // (2 per l3, 8 nodes each); a round covers one 16-node slice for all l3.
    int bid = blockIdx.x;
    int x = bid & 7, j = bid >> 3;
    int rnd = j >> 3, k = j & 7;
    int l3 = k >> 1, q = k & 1;
    int n0 = x*1024 + rnd*16 + q*8;
    if (l3 == 0)      run8<0>(n0, f1b, f2b, wt, C2, out, C2s, Asb);
    else if (l3 == 1) run8<1>(n0, f1b, f2b, wt, C2, out, C2s, Asb);
    else if (l3 == 2) run8<2>(n0, f1b, f2b, wt, C2, out, C2s, Asb);
    else              run8<3>(n0, f1b, f2b, wt, C2, out, C2s, Asb);
}

extern "C" void kernel_launch(void* const* d_in, const int* in_sizes, int n_in,
                              void* d_out, int out_size, void* d_ws, size_t ws_size,
                              hipStream_t stream) {
    const float* f10 = (const float*)d_in[0];
    const float* f20 = (const float*)d_in[1];
    const float* W0  = (const float*)d_in[2];
    const float* f11 = (const float*)d_in[3];
    const float* f21 = (const float*)d_in[4];
    const float* W1  = (const float*)d_in[5];
    const float* f12 = (const float*)d_in[6];
    const float* f22 = (const float*)d_in[7];
    const float* W2  = (const float*)d_in[8];
    const float* f13 = (const float*)d_in[9];
    const float* f23 = (const float*)d_in[10];
    const float* W3  = (const float*)d_in[11];

    float* C2 = (float*)d_ws;                                       // 6664 B
    unsigned short* wtw = (unsigned short*)((char*)d_ws + 8192);    // 1.09 MB
    unsigned short* f1b = (unsigned short*)((char*)d_ws + 1122304); // 32 MB
    unsigned short* f2b = f1b + FTOT;                               // 32 MB
    float* out = (float*)d_out;

    hipLaunchKernelGGL(cg_init, dim3(7), dim3(256), 0, stream, C2);
    hipLaunchKernelGGL(wt_prep, dim3(68*32), dim3(256), 0, stream, W0, W1, W2, W3, wtw);
    hipLaunchKernelGGL(fpack, dim3(7168, 8), dim3(256), 0, stream,
        f10, f11, f12, f13, f20, f21, f22, f23, f1b);
    hipLaunchKernelGGL(cg_main, dim3(4096), dim3(256), 0, stream,
        f1b, f2b, wtw, C2, out);
}

// Round 18
// 160.903 us; speedup vs baseline: 2.3286x; 1.5332x over previous
//
#include <hip/hip_runtime.h>

#define K_DIM 128

typedef __attribute__((ext_vector_type(8))) short short8;
typedef __attribute__((ext_vector_type(4))) float f32x4;

// ---- compile-time path tables: PATHS order = l1-major, l2, l3 ascending ----
constexpr int C_L1[34] = {0,0,0,0, 1,1,1,1,1,1,1,1,1, 2,2,2,2,2,2,2,2,2,2,2, 3,3,3,3,3,3,3,3,3,3};
constexpr int C_L2[34] = {0,1,2,3, 0,1,1,1,2,2,2,3,3, 0,1,1,1,2,2,2,2,3,3,3, 0,1,1,2,2,2,3,3,3,3};
constexpr int C_L3[34] = {0,1,2,3, 1,0,1,2,1,2,3,2,3, 2,1,2,3,0,1,2,3,1,2,3, 3,2,3,1,2,3,0,1,2,3};
constexpr int C_NP[4]  = {4,9,11,10};
constexpr int C_PL[4][11] = {
  {0,5,17,30, 0,0,0,0,0,0,0},
  {1,4,6,8,14,18,21,27,31, 0,0},
  {2,7,9,11,13,15,19,22,25,28,32},
  {3,10,12,16,20,23,24,26,29,33, 0}
};
constexpr int C_CSUM[4] = {0,8,26,48};      // 64-ch chunk base per l3
constexpr size_t FOFF[4] = {0, 1048576, 4194304, 9437184};  // per-l elem offsets
constexpr int FSZ[4] = {1048576, 3145728, 5242880, 7340032};
constexpr size_t FTOT = 16777216;           // elems per f-set

__device__ double dfactd(int n){ double r=1.0; for(int i=2;i<=n;++i) r*=(double)i; return r; }

__device__ __forceinline__ unsigned short f2bf(float x) {
    unsigned int b = __float_as_uint(x);
    return (unsigned short)((b + 0x7FFFu + ((b >> 16) & 1u)) >> 16);
}
__device__ __forceinline__ float bflo(unsigned int u){ return __uint_as_float(u << 16); }
__device__ __forceinline__ float bfhi(unsigned int u){ return __uint_as_float(u & 0xFFFF0000u); }

__device__ __forceinline__ unsigned int cvtpk(float lo, float hi) {
    unsigned int r;
    asm("v_cvt_pk_bf16_f32 %0, %1, %2" : "=v"(r) : "v"(lo), "v"(hi));
    return r;
}

// C2[p][m1i][m2i], 34*49 floats at d_ws+0
__global__ void cg_init(float* __restrict__ C2) {
    int e = blockIdx.x*blockDim.x + threadIdx.x;
    if (e >= 34*49) return;
    int p = e/49, r = e%49, m1i = r/7, m2i = r%7;
    int l1 = C_L1[p], l2 = C_L2[p], l3 = C_L3[p];
    float val = 0.f;
    if (m1i < 2*l1+1 && m2i < 2*l2+1) {
        int m1 = m1i-l1, m2 = m2i-l2, m3 = m1+m2;
        if (m3 >= -l3 && m3 <= l3) {
            double pref = sqrt((double)(2*l3+1) * dfactd(l3+l1-l2)*dfactd(l3-l1+l2)
                               * dfactd(l1+l2-l3) / dfactd(l1+l2+l3+1));
            pref *= sqrt(dfactd(l3+m3)*dfactd(l3-m3)*dfactd(l1-m1)*dfactd(l1+m1)
                         *dfactd(l2-m2)*dfactd(l2+m2));
            int kmin = max(0, max(l2-l3-m1, l1-l3+m2));
            int kmax = min(l1+l2-l3, min(l1-m1, l2+m2));
            double s = 0.0;
            for (int k=kmin;k<=kmax;++k) {
                double t = dfactd(k)*dfactd(l1+l2-l3-k)*dfactd(l1-m1-k)
                         * dfactd(l2+m2-k)*dfactd(l3-l2+m1+k)*dfactd(l3-l1-m2+k);
                s += ((k&1)? -1.0:1.0)/t;
            }
            val = (float)(pref*s);
        }
    }
    C2[e] = val;
}

// W -> bf16 transposed+swizzled tiles: chunk c elem col*64 + (kk ^ ((col&7)<<3))
__global__ void wt_prep(const float* __restrict__ W0, const float* __restrict__ W1,
                        const float* __restrict__ W2, const float* __restrict__ W3,
                        unsigned short* __restrict__ wt) {
    int b = blockIdx.x;
    int chunk = b >> 5;
    int e = ((b & 31) << 8) + threadIdx.x;
    int kk = e & 63, col = e >> 6;
    int l3 = (chunk < 8) ? 0 : (chunk < 26) ? 1 : (chunk < 48) ? 2 : 3;
    int local = chunk - C_CSUM[l3];
    int kin = local*64 + kk;
    const float* W = (l3==0)?W0:(l3==1)?W1:(l3==2)?W2:W3;
    float v = W[(size_t)kin*K_DIM + col];
    wt[(size_t)chunk*8192 + col*64 + (kk ^ ((col&7)<<3))] = f2bf(v);
}

// f1/f2 -> bf16 packed copies in ws
__global__ void fpack(const float* __restrict__ s0, const float* __restrict__ s1,
                      const float* __restrict__ s2, const float* __restrict__ s3,
                      const float* __restrict__ s4, const float* __restrict__ s5,
                      const float* __restrict__ s6, const float* __restrict__ s7,
                      unsigned short* __restrict__ dst) {
    int y = blockIdx.y;
    int l = y & 3, fi = y >> 2;
    const float* srcs[8] = {s0,s1,s2,s3,s4,s5,s6,s7};
    const float* src = srcs[y];
    int i4 = blockIdx.x*256 + threadIdx.x;
    if (i4*4 >= FSZ[l]) return;
    float4 v = reinterpret_cast<const float4*>(src)[i4];
    unsigned int u0 = (unsigned int)f2bf(v.x) | ((unsigned int)f2bf(v.y) << 16);
    unsigned int u1 = (unsigned int)f2bf(v.z) | ((unsigned int)f2bf(v.w) << 16);
    unsigned short* d = dst + fi*FTOT + FOFF[l] + (size_t)i4*4;
    *reinterpret_cast<uint2*>(d) = make_uint2(u0, u1);
}

// TP for one path (both halves): q1 resident, q2 streamed per path.
template<int L3, int PI>
__device__ __forceinline__ void tp_into(
    const unsigned int (&q1)[16][2], const unsigned int (&q2s)[7][2],
    const float* __restrict__ C2slot, unsigned char* __restrict__ Ab,
    int nodel, int chq)
{
    constexpr int P  = C_PL[L3][PI];
    constexpr int l1 = C_L1[P], l2 = C_L2[P];
    constexpr int d1 = 2*l1+1, d2 = 2*l2+1;
    constexpr int TL3 = 2*L3+1;
    #pragma unroll
    for (int h=0; h<2; ++h) {
        float xlo[d1], xhi[d1];                    // pre-extract once
        #pragma unroll
        for (int m=0;m<d1;++m) { xlo[m]=bflo(q1[l1*l1+m][h]); xhi[m]=bfhi(q1[l1*l1+m][h]); }
        float a[TL3][2];
        #pragma unroll
        for (int mt=0;mt<TL3;++mt){ a[mt][0]=0.f; a[mt][1]=0.f; }
        #pragma unroll
        for (int m2i=0; m2i<d2; ++m2i) {
            float y0 = bflo(q2s[m2i][h]);
            float y1 = bfhi(q2s[m2i][h]);
            #pragma unroll
            for (int m1i=0; m1i<d1; ++m1i) {
                int mt = (m1i-l1) + (m2i-l2) + L3;
                if (mt >= 0 && mt < TL3) {         // folds at compile time
                    float c = C2slot[m1i*7 + m2i];
                    a[mt][0] = fmaf(c*xlo[m1i], y0, a[mt][0]);
                    a[mt][1] = fmaf(c*xhi[m1i], y1, a[mt][1]);
                }
            }
        }
        #pragma unroll
        for (int mt=0; mt<TL3; ++mt) {
            int row = nodel*TL3 + mt;
            *reinterpret_cast<unsigned int*>(
                Ab + row*256 + h*128 + ((chq*4) ^ ((row&7)<<4))) = cvtpk(a[mt][0], a[mt][1]);
        }
    }
}

template<int L3, int PI>
__device__ __forceinline__ void stream_f2(
    const unsigned short* __restrict__ f2b, int n0, int nodel, int chq,
    unsigned int (&q2s)[7][2])
{
    constexpr int P  = C_PL[L3][PI];
    constexpr int l2 = C_L2[P];
    constexpr int d2 = 2*l2+1;
    const unsigned short* g2 = f2b + FOFF[l2] + (size_t)(n0+nodel)*(d2*128) + chq*2;
    #pragma unroll
    for (int m=0;m<d2;++m) {
        q2s[m][0] = *reinterpret_cast<const unsigned int*>(g2 + m*128);
        q2s[m][1] = *reinterpret_cast<const unsigned int*>(g2 + m*128 + 64);
    }
}

template<int L3, int PI>
__device__ __forceinline__ void load_wf(const unsigned short* __restrict__ wt,
                                        int col, int lg, short8 (&wf)[4]) {
    const int wkey = (col&7)<<4;
    const unsigned char* wb0 = (const unsigned char*)(wt + (size_t)(C_CSUM[L3] + PI*2    )*8192);
    const unsigned char* wb1 = (const unsigned char*)(wt + (size_t)(C_CSUM[L3] + PI*2 + 1)*8192);
    wf[0] = *reinterpret_cast<const short8*>(wb0 + col*128 + ((16*lg     ) ^ wkey));
    wf[1] = *reinterpret_cast<const short8*>(wb0 + col*128 + ((16*lg + 64) ^ wkey));
    wf[2] = *reinterpret_cast<const short8*>(wb1 + col*128 + ((16*lg     ) ^ wkey));
    wf[3] = *reinterpret_cast<const short8*>(wb1 + col*128 + ((16*lg + 64) ^ wkey));
}

template<int L3>
__device__ __forceinline__ void mfma_from(
    const unsigned char* __restrict__ Ab, const short8 (&wf)[4],
    int lr, int lg, f32x4 (&cacc)[2*L3+1])
{
    constexpr int TL3 = 2*L3+1;
    #pragma unroll
    for (int kst=0; kst<4; ++kst) {
        #pragma unroll
        for (int rt=0; rt<TL3; ++rt) {
            int arow = 16*rt + lr;
            short8 af = *reinterpret_cast<const short8*>(
                Ab + arow*256 + ((16*lg + 64*kst) ^ ((arow&7)<<4)));
            cacc[rt] = __builtin_amdgcn_mfma_f32_16x16x32_bf16(af, wf[kst], cacc[rt], 0, 0, 0);
        }
    }
}

// Pipelined path chain: {wf(PI); C2s(PI+2) preload; f2(PI+1) stream;
// TP(PI+1)->buf[(PI+1)&1]; MFMA(PI)<-buf[PI&1]; barrier}
template<int L3, int PI>
__device__ __forceinline__ void pipe(
    const unsigned int (&q1)[16][2], unsigned int (&q2s)[7][2],
    const unsigned short* __restrict__ f2b,
    const unsigned short* __restrict__ wt, const float* __restrict__ C2,
    float (&C2s)[2][49], unsigned char* A0, unsigned char* A1,
    int tid, int n0, int nodel, int chq, int col, int lr, int lg,
    f32x4 (&cacc)[2*L3+1])
{
    constexpr int NP = C_NP[L3];
    short8 wf[4];
    load_wf<L3, PI>(wt, col, lg, wf);
    if constexpr (PI+2 < NP) {
        if (tid < 49) C2s[PI&1][tid] = C2[C_PL[L3][PI+2]*49 + tid];
    }
    if constexpr (PI+1 < NP) {
        stream_f2<L3, PI+1>(f2b, n0, nodel, chq, q2s);
        tp_into<L3, PI+1>(q1, q2s, C2s[(PI+1)&1], ((PI+1)&1) ? A1 : A0, nodel, chq);
    }
    mfma_from<L3>((PI&1) ? A1 : A0, wf, lr, lg, cacc);
    __syncthreads();
    if constexpr (PI+1 < NP)
        pipe<L3, PI+1>(q1, q2s, f2b, wt, C2, C2s, A0, A1,
                       tid, n0, nodel, chq, col, lr, lg, cacc);
}

template<int L3>
__device__ __forceinline__ void run16(
    int n0,
    const unsigned short* __restrict__ f1b, const unsigned short* __restrict__ f2b,
    const unsigned short* __restrict__ wt, const float* __restrict__ C2,
    float* __restrict__ out, float (&C2s)[2][49], unsigned char* Asb)
{
    constexpr int TL3 = 2*L3+1;
    constexpr int NP  = C_NP[L3];
    const int tid   = threadIdx.x;
    const int nodel = tid >> 5;
    const int chq   = tid & 31;
    const int lane  = tid & 63, wid = tid >> 6;
    const int lr    = lane & 15, lg = lane >> 4;
    const int col   = 16*wid + lr;
    constexpr size_t OB = FOFF[L3];
    unsigned char* A0 = Asb;
    unsigned char* A1 = Asb + 28672;

    // prologue: resident f1 loads only (q2 streamed per path)
    unsigned int q1[16][2];
    #pragma unroll
    for (int l=0; l<4; ++l) {
        const unsigned short* g1 = f1b + FOFF[l] + (size_t)(n0+nodel)*((2*l+1)*128) + chq*2;
        #pragma unroll
        for (int m=0; m<2*l+1; ++m) {
            q1[l*l+m][0] = *reinterpret_cast<const unsigned int*>(g1 + m*128);
            q1[l*l+m][1] = *reinterpret_cast<const unsigned int*>(g1 + m*128 + 64);
        }
    }
    unsigned int q2s[7][2];

    f32x4 cacc[TL3];
    #pragma unroll
    for (int rt=0; rt<TL3; ++rt) cacc[rt] = (f32x4){0.f,0.f,0.f,0.f};

    if (tid < 49) {
        C2s[0][tid] = C2[C_PL[L3][0]*49 + tid];
        if constexpr (NP > 1) C2s[1][tid] = C2[C_PL[L3][1]*49 + tid];
    }
    __syncthreads();
    stream_f2<L3, 0>(f2b, n0, nodel, chq, q2s);
    tp_into<L3, 0>(q1, q2s, C2s[0], A0, nodel, chq);
    __syncthreads();
    pipe<L3, 0>(q1, q2s, f2b, wt, C2, C2s, A0, A1,
                tid, n0, nodel, chq, col, lr, lg, cacc);

    // epilogue: padded LDS restage (stride 132) in 4-row-tile batches ->
    // full-line coalesced stores + bf16 residual
    float* S = reinterpret_cast<float*>(Asb);
    const unsigned short* __restrict__ fr = f1b + OB;
    #pragma unroll
    for (int rt0=0; rt0<TL3; rt0+=4) {
        const int bn = (TL3 - rt0 < 4) ? (TL3 - rt0) : 4;
        #pragma unroll
        for (int rtl=0; rtl<4; ++rtl) {
            if (rtl < bn) {
                #pragma unroll
                for (int i=0;i<4;++i)
                    S[(rtl*16 + 4*lg + i)*132 + col] = cacc[rt0+rtl][i];
            }
        }
        __syncthreads();
        #pragma unroll
        for (int it=0; it<4; ++it) {
            if (it < bn) {
                int s = tid + it*512;
                int rows = s >> 5, cq = (s & 31) * 4;
                int gr = n0*TL3 + (rt0 + (rows >> 4))*16 + (rows & 15);
                size_t ro = (size_t)gr * K_DIM;
                float4 v = *reinterpret_cast<const float4*>(&S[rows*132 + cq]);
                uint2 rb = *reinterpret_cast<const uint2*>(fr + ro + cq);
                v.x += bflo(rb.x); v.y += bfhi(rb.x);
                v.z += bflo(rb.y); v.w += bfhi(rb.y);
                *reinterpret_cast<float4*>(&out[OB + ro + cq]) = v;
            }
        }
        __syncthreads();
    }
}

__global__ __launch_bounds__(512) void cg_main(
    const unsigned short* __restrict__ f1b, const unsigned short* __restrict__ f2b,
    const unsigned short* __restrict__ wt,
    const float* __restrict__ C2, float* __restrict__ out)
{
    __shared__ __align__(16) unsigned char Asb[2*28672];  // A dbuf / epilogue stage
    __shared__ float C2s[2][49];

    // Schedule: x = XCD (bid&7); 16 rounds x 16 blocks (4 per l3, 16 nodes each);
    // one round covers the same 64-node slice for all l3 -> L2-resident f reuse.
    int bid = blockIdx.x;
    int x = bid & 7, j = bid >> 3;
    int rnd = j >> 4, k = j & 15;
    int l3 = k >> 2, q = k & 3;
    int n0 = x*1024 + rnd*64 + q*16;
    if (l3 == 0)      run16<0>(n0, f1b, f2b, wt, C2, out, C2s, Asb);
    else if (l3 == 1) run16<1>(n0, f1b, f2b, wt, C2, out, C2s, Asb);
    else if (l3 == 2) run16<2>(n0, f1b, f2b, wt, C2, out, C2s, Asb);
    else              run16<3>(n0, f1b, f2b, wt, C2, out, C2s, Asb);
}

extern "C" void kernel_launch(void* const* d_in, const int* in_sizes, int n_in,
                              void* d_out, int out_size, void* d_ws, size_t ws_size,
                              hipStream_t stream) {
    const float* f10 = (const float*)d_in[0];
    const float* f20 = (const float*)d_in[1];
    const float* W0  = (const float*)d_in[2];
    const float* f11 = (const float*)d_in[3];
    const float* f21 = (const float*)d_in[4];
    const float* W1  = (const float*)d_in[5];
    const float* f12 = (const float*)d_in[6];
    const float* f22 = (const float*)d_in[7];
    const float* W2  = (const float*)d_in[8];
    const float* f13 = (const float*)d_in[9];
    const float* f23 = (const float*)d_in[10];
    const float* W3  = (const float*)d_in[11];

    float* C2 = (float*)d_ws;                                       // 6664 B
    unsigned short* wtw = (unsigned short*)((char*)d_ws + 8192);    // 1.09 MB
    unsigned short* f1b = (unsigned short*)((char*)d_ws + 1122304); // 32 MB
    unsigned short* f2b = f1b + FTOT;                               // 32 MB
    float* out = (float*)d_out;

    hipLaunchKernelGGL(cg_init, dim3(7), dim3(256), 0, stream, C2);
    hipLaunchKernelGGL(wt_prep, dim3(68*32), dim3(256), 0, stream, W0, W1, W2, W3, wtw);
    hipLaunchKernelGGL(fpack, dim3(7168, 8), dim3(256), 0, stream,
        f10, f11, f12, f13, f20, f21, f22, f23, f1b);
    hipLaunchKernelGGL(cg_main, dim3(2048), dim3(512), 0, stream,
        f1b, f2b, wtw, C2, out);
}